// Round 5
// baseline (1090.413 us; speedup 1.0000x reference)
//
#include <hip/hip_runtime.h>
#include <hip/hip_cooperative_groups.h>
#include <math.h>

// FermiNet-like forward, N=1024, DIM=3, all fp32.
//
// v5: occupancy + launch-tail round.
//  * k2: m=2 i-rows/thread (was 4), 16 outer iters, live ~70 floats,
//    __launch_bounds__(256,4) -> VGPR<=128 -> 4 waves/SIMD (v4: VGPR 212 ->
//    ~1 wave/SIMD, VALUBusy 55%). Biases hoisted to registers (were re-read
//    from LDS every iteration). LDS/block 24.4 KB -> 4 blocks/CU resident.
//  * h1 chain (l0+lx1+lx2+lx3) fused into ONE cooperative kernel with
//    grid.sync() between layers: 6 launches -> 3, kills ~3 launch gaps.
// Unchanged (validated: 0 bank conflicts, absmax 1.9e-6): XOR-swizzled sH
// h-exchange, barrier-free k2 main loop, TROW row-major trig tables.

#define NP 1024
namespace cg = cooperative_groups;

// ---- workspace offsets (in floats) ----
static const size_t OF_TROW = 0;                    // NP*56 row-major trig
static const size_t OF_CSUM = OF_TROW + NP*56;      // 24  sum_i cos
static const size_t OF_SSUM = OF_CSUM + 24;         // 24  sum_i sin
static const size_t OF_HSUM = OF_SSUM + 24;         // 3*64  h1 row-sum per layer
static const size_t OF_RACC = OF_HSUM + 192;        // 1024  sum_i r(i,j)
static const size_t OF_M0   = OF_RACC + NP;         // 1024*32 sum_i h2 stage0
static const size_t OF_M1   = OF_M0 + NP*32;        // 1024*32 stage1
static const size_t OF_M2   = OF_M1 + NP*32;        // 1024*32 stage2
static const size_t OF_H1A  = OF_M2 + NP*32;        // 1024*64
static const size_t OF_H1B  = OF_H1A + NP*64;       // 1024*64
// end: OF_H1B + NP*64 = 287984 floats (~1.15 MB)

__device__ __forceinline__ float ftanh(float x) {
    float e = __expf(2.0f * x);
    return 1.0f - __fdividef(2.0f, e + 1.0f);
}

// ---------------------------------------------------------------------------
// K1: per-particle trig rows (TROW[i][56]) + column sums + zero HSUM.
// ---------------------------------------------------------------------------
__global__ __launch_bounds__(1024) void k1_tables(
    const float* __restrict__ X,
    float* __restrict__ TROW,
    float* __restrict__ CSUM, float* __restrict__ SSUM,
    float* __restrict__ HSUM)
{
    const int i = threadIdx.x;
    float ck[24], sk[24], cp[3], sp[3];
#pragma unroll
    for (int d = 0; d < 3; ++d) {
        float x = X[i*3 + d];
        sincospif(x, &sp[d], &cp[d]);
#pragma unroll
        for (int k = 0; k < 8; ++k) {
            float s, c;
            sincospif(2.0f*(float)(k+1)*x, &s, &c);
            ck[k*3 + d] = c;  sk[k*3 + d] = s;
        }
    }
    float4* row = (float4*)(TROW + (size_t)i*56);
#pragma unroll
    for (int t = 0; t < 12; ++t)
        row[t] = make_float4(ck[2*t], sk[2*t], ck[2*t+1], sk[2*t+1]);
    row[12] = make_float4(cp[0], sp[0], cp[1], sp[1]);
    row[13] = make_float4(cp[2], sp[2], 0.f, 0.f);

    __shared__ float part[48*16];
    const int lane = i & 63, wv = i >> 6;
#pragma unroll
    for (int v = 0; v < 24; ++v) {
        float a = ck[v], b = sk[v];
#pragma unroll
        for (int off = 32; off; off >>= 1) {
            a += __shfl_down(a, off, 64);
            b += __shfl_down(b, off, 64);
        }
        if (lane == 0) { part[v*16 + wv] = a; part[(24+v)*16 + wv] = b; }
    }
    __syncthreads();
    if (i < 48) {
        float s = 0.f;
#pragma unroll
        for (int w = 0; w < 16; ++w) s += part[i*16 + w];
        if (i < 24) CSUM[i] = s; else SSUM[i-24] = s;
    }
    if (i < 192) HSUM[i] = 0.0f;
}

// ---------------------------------------------------------------------------
// K2: pair kernel. Block = column j. q = tid&7 (cols q*4..q*4+3), g = tid>>3
// (0..31). i = it*64 + m*32 + g, m=0..1, it=0..15. No barriers in main loop.
// ---------------------------------------------------------------------------
__global__ __launch_bounds__(256, 4) void k2_pairs(
    const float* __restrict__ W20, const float* __restrict__ b20,
    const float* __restrict__ W21, const float* __restrict__ b21,
    const float* __restrict__ W22, const float* __restrict__ b22,
    const float* __restrict__ TROW,
    float* __restrict__ RACC, float* __restrict__ M0,
    float* __restrict__ M1, float* __restrict__ M2)
{
    __shared__ __align__(16) float sW0[49*32];
    __shared__ __align__(16) float sW1[32*32];
    __shared__ __align__(16) float sW2[32*32];
    __shared__ __align__(16) float sH[2*32*32];   // 64 rows x 32 f, XOR-swizzled
    __shared__ __align__(16) float sJ[56];        // row j of TROW
    __shared__ float sPart[4][97];

    const int tid = threadIdx.x;
    const int j = blockIdx.x;
    const int q = tid & 7;
    const int g = tid >> 3;          // 0..31
    const int c0 = q * 4;
    const int gx = g & 7;

    for (int v = tid; v < 49*32; v += 256) sW0[v] = W20[v];
    for (int v = tid; v < 32*32; v += 256) sW1[v] = W21[v];
    for (int v = tid; v < 32*32; v += 256) sW2[v] = W22[v];
    if (tid < 14) ((float4*)sJ)[tid] = ((const float4*)(TROW + (size_t)j*56))[tid];

    // biases: registers, loop-invariant (v4 re-read LDS every iter)
    float zb0[4], zb1[4], zb2[4];
    *(float4*)zb0 = *(const float4*)(b20 + c0);
    *(float4*)zb1 = *(const float4*)(b21 + c0);
    *(float4*)zb2 = *(const float4*)(b22 + c0);
    __syncthreads();

    float4* sH4 = (float4*)sH;        // index: (m*32+g)*8 + (slot ^ gx)

    float a0[4], a1[4], a2[4];
#pragma unroll
    for (int u = 0; u < 4; ++u) { a0[u] = 0.f; a1[u] = 0.f; a2[u] = 0.f; }
    float racc = 0.f;

#pragma unroll 1
    for (int it = 0; it < 16; ++it) {
        const int ib = it*64 + g;            // rows ib, ib+32
        const float4* row0 = (const float4*)(TROW + (size_t)(ib +  0)*56);
        const float4* row1 = (const float4*)(TROW + (size_t)(ib + 32)*56);

        float z[2][4];
#pragma unroll
        for (int m = 0; m < 2; ++m) {
            z[m][0] = zb0[0]; z[m][1] = zb0[1]; z[m][2] = zb0[2]; z[m][3] = zb0[3];
        }

        // ---- r feature (8x redundant across q-lanes) ----
        float rv[2];
#pragma unroll
        for (int m = 0; m < 2; ++m) {
            const float4* rw = m ? row1 : row0;
            float4 pa = rw[12], pb = rw[13];
            float sd0 = fmaf(pa.y, sJ[48], -(pa.x * sJ[49]));
            float sd1 = fmaf(pa.w, sJ[50], -(pa.z * sJ[51]));
            float sd2 = fmaf(pb.y, sJ[52], -(pb.x * sJ[53]));
            float r2 = fmaf(sd0, sd0, fmaf(sd1, sd1, sd2*sd2));
            rv[m] = sqrtf(r2);
            racc += rv[m];
        }
        {
            const float4 w = *(const float4*)(sW0 + c0);   // row 0
#pragma unroll
            for (int m = 0; m < 2; ++m) {
                z[m][0]=fmaf(rv[m],w.x,z[m][0]); z[m][1]=fmaf(rv[m],w.y,z[m][1]);
                z[m][2]=fmaf(rv[m],w.z,z[m][2]); z[m][3]=fmaf(rv[m],w.w,z[m][3]);
            }
        }
        // ---- 48 cos/sin features, 2 kd per float4 chunk ----
#pragma unroll
        for (int t = 0; t < 12; ++t) {
            const float4 cs0 = row0[t], cs1 = row1[t];
#pragma unroll
            for (int sub = 0; sub < 2; ++sub) {
                const int kd = 2*t + sub;
                const int k = kd/3, d = kd - k*3;
                const float ckj = sJ[2*kd], skj = sJ[2*kd+1];
                const float4 wc  = *(const float4*)(sW0 + (1 + k*6 + d)*32 + c0);
                const float4 wsn = *(const float4*)(sW0 + (4 + k*6 + d)*32 + c0);
#pragma unroll
                for (int m = 0; m < 2; ++m) {
                    const float4 cs = m ? cs1 : cs0;
                    float ci = sub ? cs.z : cs.x;
                    float si = sub ? cs.w : cs.y;
                    float cc = fmaf(ci, ckj, si * skj);
                    float ss = fmaf(si, ckj, -(ci * skj));
                    z[m][0] = fmaf(cc, wc.x, fmaf(ss, wsn.x, z[m][0]));
                    z[m][1] = fmaf(cc, wc.y, fmaf(ss, wsn.y, z[m][1]));
                    z[m][2] = fmaf(cc, wc.z, fmaf(ss, wsn.z, z[m][2]));
                    z[m][3] = fmaf(cc, wc.w, fmaf(ss, wsn.w, z[m][3]));
                }
            }
        }

        // ---- layer 0 tanh; publish h0 to sH ----
        float h0own[2][4];
#pragma unroll
        for (int m = 0; m < 2; ++m) {
            float4 hv;
            hv.x = ftanh(z[m][0]); hv.y = ftanh(z[m][1]);
            hv.z = ftanh(z[m][2]); hv.w = ftanh(z[m][3]);
            h0own[m][0]=hv.x; h0own[m][1]=hv.y; h0own[m][2]=hv.z; h0own[m][3]=hv.w;
            a0[0]+=hv.x; a0[1]+=hv.y; a0[2]+=hv.z; a0[3]+=hv.w;
            sH4[(m*32+g)*8 + (q ^ gx)] = hv;
            z[m][0]=zb1[0]; z[m][1]=zb1[1]; z[m][2]=zb1[2]; z[m][3]=zb1[3];
        }

        // ---- layer 1 matvec (sH written by own wave; no barrier needed) ----
#pragma unroll
        for (int kc = 0; kc < 8; ++kc) {
            const float4 w0 = *(const float4*)(sW1 + (kc*4+0)*32 + c0);
            const float4 w1 = *(const float4*)(sW1 + (kc*4+1)*32 + c0);
            const float4 w2 = *(const float4*)(sW1 + (kc*4+2)*32 + c0);
            const float4 w3 = *(const float4*)(sW1 + (kc*4+3)*32 + c0);
#pragma unroll
            for (int m = 0; m < 2; ++m) {
                const float4 hc = sH4[(m*32+g)*8 + (kc ^ gx)];
                z[m][0]=fmaf(hc.x,w0.x,fmaf(hc.y,w1.x,fmaf(hc.z,w2.x,fmaf(hc.w,w3.x,z[m][0]))));
                z[m][1]=fmaf(hc.x,w0.y,fmaf(hc.y,w1.y,fmaf(hc.z,w2.y,fmaf(hc.w,w3.y,z[m][1]))));
                z[m][2]=fmaf(hc.x,w0.z,fmaf(hc.y,w1.z,fmaf(hc.z,w2.z,fmaf(hc.w,w3.z,z[m][2]))));
                z[m][3]=fmaf(hc.x,w0.w,fmaf(hc.y,w1.w,fmaf(hc.z,w2.w,fmaf(hc.w,w3.w,z[m][3]))));
            }
        }
        float h1own[2][4];
#pragma unroll
        for (int m = 0; m < 2; ++m) {
            float4 hv;
            hv.x = ftanh(z[m][0]) + h0own[m][0];
            hv.y = ftanh(z[m][1]) + h0own[m][1];
            hv.z = ftanh(z[m][2]) + h0own[m][2];
            hv.w = ftanh(z[m][3]) + h0own[m][3];
            h1own[m][0]=hv.x; h1own[m][1]=hv.y; h1own[m][2]=hv.z; h1own[m][3]=hv.w;
            a1[0]+=hv.x; a1[1]+=hv.y; a1[2]+=hv.z; a1[3]+=hv.w;
            sH4[(m*32+g)*8 + (q ^ gx)] = hv;       // overwrite h0 (reads done)
            z[m][0]=zb2[0]; z[m][1]=zb2[1]; z[m][2]=zb2[2]; z[m][3]=zb2[3];
        }

        // ---- layer 2 matvec ----
#pragma unroll
        for (int kc = 0; kc < 8; ++kc) {
            const float4 w0 = *(const float4*)(sW2 + (kc*4+0)*32 + c0);
            const float4 w1 = *(const float4*)(sW2 + (kc*4+1)*32 + c0);
            const float4 w2 = *(const float4*)(sW2 + (kc*4+2)*32 + c0);
            const float4 w3 = *(const float4*)(sW2 + (kc*4+3)*32 + c0);
#pragma unroll
            for (int m = 0; m < 2; ++m) {
                const float4 hc = sH4[(m*32+g)*8 + (kc ^ gx)];
                z[m][0]=fmaf(hc.x,w0.x,fmaf(hc.y,w1.x,fmaf(hc.z,w2.x,fmaf(hc.w,w3.x,z[m][0]))));
                z[m][1]=fmaf(hc.x,w0.y,fmaf(hc.y,w1.y,fmaf(hc.z,w2.y,fmaf(hc.w,w3.y,z[m][1]))));
                z[m][2]=fmaf(hc.x,w0.z,fmaf(hc.y,w1.z,fmaf(hc.z,w2.z,fmaf(hc.w,w3.z,z[m][2]))));
                z[m][3]=fmaf(hc.x,w0.w,fmaf(hc.y,w1.w,fmaf(hc.z,w2.w,fmaf(hc.w,w3.w,z[m][3]))));
            }
        }
#pragma unroll
        for (int m = 0; m < 2; ++m) {
            a2[0] += ftanh(z[m][0]) + h1own[m][0];
            a2[1] += ftanh(z[m][1]) + h1own[m][1];
            a2[2] += ftanh(z[m][2]) + h1own[m][2];
            a2[3] += ftanh(z[m][3]) + h1own[m][3];
        }
    }

    // ---- reduction: over g within wave (lane bits 3..5), then 4 waves ----
    const int lane = tid & 63, wid = tid >> 6;
#pragma unroll
    for (int u = 0; u < 4; ++u) {
#pragma unroll
        for (int mask = 8; mask < 64; mask <<= 1) {
            a0[u] += __shfl_xor(a0[u], mask, 64);
            a1[u] += __shfl_xor(a1[u], mask, 64);
            a2[u] += __shfl_xor(a2[u], mask, 64);
        }
    }
#pragma unroll
    for (int mask = 1; mask < 64; mask <<= 1) racc += __shfl_xor(racc, mask, 64);

    if (lane < 8) {
#pragma unroll
        for (int u = 0; u < 4; ++u) {
            sPart[wid][1  + lane*4 + u] = a0[u];
            sPart[wid][33 + lane*4 + u] = a1[u];
            sPart[wid][65 + lane*4 + u] = a2[u];
        }
    }
    if (lane == 0) sPart[wid][0] = racc;
    __syncthreads();
    if (tid < 97) {
        float s = sPart[0][tid] + sPart[1][tid] + sPart[2][tid] + sPart[3][tid];
        if (tid == 0)      RACC[j] = s * 0.125f;     // r computed 8x redundantly
        else if (tid < 33) M0[j*32 + (tid-1)]  = s;
        else if (tid < 65) M1[j*32 + (tid-33)] = s;
        else               M2[j*32 + (tid-65)] = s;
    }
}

// ---------------------------------------------------------------------------
// Fused h1 path: one cooperative kernel, 32 blocks x 256 threads.
// Thread = (row j, 8-channel chunk qq). grid.sync() between layers.
// ---------------------------------------------------------------------------
#define FMA8(fv, wptr) do { \
    const float4* w4_ = (const float4*)(wptr); \
    float4 a_ = w4_[0], b_ = w4_[1]; \
    z[0]=fmaf((fv),a_.x,z[0]); z[1]=fmaf((fv),a_.y,z[1]); \
    z[2]=fmaf((fv),a_.z,z[2]); z[3]=fmaf((fv),a_.w,z[3]); \
    z[4]=fmaf((fv),b_.x,z[4]); z[5]=fmaf((fv),b_.y,z[5]); \
    z[6]=fmaf((fv),b_.z,z[6]); z[7]=fmaf((fv),b_.w,z[7]); \
} while (0)

__device__ __forceinline__ void hsum_atomic(float* HS, const float h[8],
                                            int tid, int c0) {
    float hs[8];
#pragma unroll
    for (int u = 0; u < 8; ++u) {
        hs[u] = h[u];
#pragma unroll
        for (int mask = 8; mask < 64; mask <<= 1)
            hs[u] += __shfl_xor(hs[u], mask, 64);
    }
    if (((tid & 63) >> 3) == 0) {
#pragma unroll
        for (int u = 0; u < 8; ++u) atomicAdd(&HS[c0 + u], hs[u]);
    }
}

__device__ __forceinline__ void lx_body(
    int j, int c0, int tid,
    const float* __restrict__ W, const float* __restrict__ b,
    const float* __restrict__ hin, const float* __restrict__ HSin,
    const float* __restrict__ M,
    float* __restrict__ hout, float* __restrict__ HSout)
{
    const float inv_n = 1.0f/1024.0f;
    float z[8];
#pragma unroll
    for (int u = 0; u < 8; ++u) z[u] = b[c0+u];
    const float* hrow = hin + j*64;
#pragma unroll 4
    for (int p = 0; p < 64; ++p) FMA8(hrow[p], W + p*64 + c0);
#pragma unroll 4
    for (int p = 0; p < 64; ++p) FMA8(HSin[p]*inv_n, W + (64+p)*64 + c0);
    const float* mrow = M + j*32;
#pragma unroll 4
    for (int p = 0; p < 32; ++p) FMA8(mrow[p]*inv_n, W + (128+p)*64 + c0);
    float h[8];
#pragma unroll
    for (int u = 0; u < 8; ++u) {
        h[u] = ftanh(z[u]) + hrow[c0+u];      // residual
        hout[j*64 + c0 + u] = h[u];
    }
    if (HSout) hsum_atomic(HSout, h, tid, c0);
}

__global__ __launch_bounds__(256) void h1_fused(
    const float* __restrict__ Tsc,
    const float* __restrict__ W10, const float* __restrict__ b10,
    const float* __restrict__ W11, const float* __restrict__ b11,
    const float* __restrict__ W12, const float* __restrict__ b12,
    const float* __restrict__ W13, const float* __restrict__ b13,
    const float* __restrict__ Wf,  const float* __restrict__ X,
    const float* __restrict__ TROW,
    const float* __restrict__ CSUM, const float* __restrict__ SSUM,
    const float* __restrict__ RACC,
    const float* __restrict__ M0, const float* __restrict__ M1,
    const float* __restrict__ M2,
    float* __restrict__ H1A, float* __restrict__ H1B,
    float* __restrict__ HSUM, float* __restrict__ out)
{
    cg::grid_group gg = cg::this_grid();
    const int tid = threadIdx.x;
    const int gid = blockIdx.x*256 + tid;
    const int j = gid >> 3, qq = gid & 7, c0 = qq*8;
    const float inv_n = 1.0f/1024.0f;

    // ---------------- phase 0: layer 0 ----------------
    {
        const float t = Tsc[0];
        float z[8];
#pragma unroll
        for (int u = 0; u < 8; ++u) z[u] = b10[c0+u];
        FMA8(t, W10 + 0*64 + c0);
        FMA8(t, W10 + 17*64 + c0);
#pragma unroll
        for (int k = 0; k < 8; ++k) {
            float s, c; sincospif(2.0f*(float)(k+1)*t, &s, &c);
            FMA8(c, W10 + (1+2*k)*64 + c0);
            FMA8(c, W10 + (18+2*k)*64 + c0);
            FMA8(s, W10 + (2+2*k)*64 + c0);
            FMA8(s, W10 + (19+2*k)*64 + c0);
        }
        FMA8(RACC[j]*inv_n, W10 + 34*64 + c0);
        const float4* rj = (const float4*)(TROW + (size_t)j*56);
#pragma unroll
        for (int tt = 0; tt < 12; ++tt) {
            float4 v = rj[tt];
#pragma unroll
            for (int sub = 0; sub < 2; ++sub) {
                const int kd = 2*tt + sub;
                float cj = sub ? v.z : v.x;
                float sj = sub ? v.w : v.y;
                float Cb = CSUM[kd]*inv_n, Sb = SSUM[kd]*inv_n;
                float cm = fmaf(cj, Cb, sj*Sb);
                float sm = fmaf(Sb, cj, -(Cb*sj));
                int k = kd/3, d = kd - k*3;
                FMA8(cm, W10 + (35 + k*6 + d)*64 + c0);
                FMA8(sm, W10 + (38 + k*6 + d)*64 + c0);
            }
        }
        float h[8];
#pragma unroll
        for (int u = 0; u < 8; ++u) {
            h[u] = ftanh(z[u]);                  // layer 0: no residual
            H1A[j*64 + c0 + u] = h[u];
        }
        hsum_atomic(HSUM + 0*64, h, tid, c0);
    }
    gg.sync();
    // ---------------- phase 1: layer 1 ----------------
    lx_body(j, c0, tid, W11, b11, H1A, HSUM + 0*64, M0, H1B, HSUM + 1*64);
    gg.sync();
    // ---------------- phase 2: layer 2 ----------------
    lx_body(j, c0, tid, W12, b12, H1B, HSUM + 1*64, M1, H1A, HSUM + 2*64);
    gg.sync();
    // ---------------- phase 3: layer 3 + output ----------------
    {
        float z[8];
#pragma unroll
        for (int u = 0; u < 8; ++u) z[u] = b13[c0+u];
        const float* hrow = H1A + j*64;
#pragma unroll 4
        for (int p = 0; p < 64; ++p) FMA8(hrow[p], W13 + p*64 + c0);
        const float* HSin = HSUM + 2*64;
#pragma unroll 4
        for (int p = 0; p < 64; ++p) FMA8(HSin[p]*inv_n, W13 + (64+p)*64 + c0);
        const float* mrow = M2 + j*32;
#pragma unroll 4
        for (int p = 0; p < 32; ++p) FMA8(mrow[p]*inv_n, W13 + (128+p)*64 + c0);
        float h[8];
#pragma unroll
        for (int u = 0; u < 8; ++u) h[u] = ftanh(z[u]) + hrow[c0+u];

        __shared__ float red[256][3];
        float p0 = 0.f, p1 = 0.f, p2 = 0.f;
#pragma unroll
        for (int u = 0; u < 8; ++u) {
            float hv = h[u];
            const float* wf = Wf + (c0+u)*3;
            p0 = fmaf(hv, wf[0], p0);
            p1 = fmaf(hv, wf[1], p1);
            p2 = fmaf(hv, wf[2], p2);
        }
        red[tid][0] = p0; red[tid][1] = p1; red[tid][2] = p2;
        __syncthreads();
        if (qq == 0) {
            float s0 = 0.f, s1 = 0.f, s2 = 0.f;
#pragma unroll
            for (int r = 0; r < 8; ++r) {
                s0 += red[tid+r][0]; s1 += red[tid+r][1]; s2 += red[tid+r][2];
            }
#pragma unroll
            for (int d = 0; d < 3; ++d) {
                float fx = 2.0f * X[j*3 + d];
                fx = fminf(fmaxf(fx, -10.0f), 10.0f);
                float s = (d == 0 ? s0 : (d == 1 ? s1 : s2));
                out[j*3 + d] = -s * fx;
            }
        }
    }
}

// ---------------------------------------------------------------------------
extern "C" void kernel_launch(void* const* d_in, const int* in_sizes, int n_in,
                              void* d_out, int out_size, void* d_ws, size_t ws_size,
                              hipStream_t stream)
{
    const float* X   = (const float*)d_in[0];
    const float* Tsc = (const float*)d_in[1];
    const float* W10 = (const float*)d_in[2];  const float* b10 = (const float*)d_in[3];
    const float* W11 = (const float*)d_in[4];  const float* b11 = (const float*)d_in[5];
    const float* W12 = (const float*)d_in[6];  const float* b12 = (const float*)d_in[7];
    const float* W13 = (const float*)d_in[8];  const float* b13 = (const float*)d_in[9];
    const float* W20 = (const float*)d_in[10]; const float* b20 = (const float*)d_in[11];
    const float* W21 = (const float*)d_in[12]; const float* b21 = (const float*)d_in[13];
    const float* W22 = (const float*)d_in[14]; const float* b22 = (const float*)d_in[15];
    const float* Wf  = (const float*)d_in[16];

    float* ws  = (float*)d_ws;
    float* out = (float*)d_out;

    float* TROW = ws + OF_TROW;
    float* CSUM = ws + OF_CSUM; float* SSUM = ws + OF_SSUM;
    float* HSUM = ws + OF_HSUM; float* RACC = ws + OF_RACC;
    float* M0 = ws + OF_M0; float* M1 = ws + OF_M1; float* M2 = ws + OF_M2;
    float* H1A = ws + OF_H1A; float* H1B = ws + OF_H1B;

    k1_tables<<<1, 1024, 0, stream>>>(X, TROW, CSUM, SSUM, HSUM);
    k2_pairs<<<NP, 256, 0, stream>>>(W20, b20, W21, b21, W22, b22,
                                     TROW, RACC, M0, M1, M2);

    void* args[] = {
        (void*)&Tsc,
        (void*)&W10, (void*)&b10, (void*)&W11, (void*)&b11,
        (void*)&W12, (void*)&b12, (void*)&W13, (void*)&b13,
        (void*)&Wf,  (void*)&X,
        (void*)&TROW, (void*)&CSUM, (void*)&SSUM, (void*)&RACC,
        (void*)&M0, (void*)&M1, (void*)&M2,
        (void*)&H1A, (void*)&H1B, (void*)&HSUM, (void*)&out
    };
    hipLaunchCooperativeKernel((const void*)h1_fused, dim3(32), dim3(256),
                               args, 0, stream);
}

// Round 6
// 1056.276 us; speedup vs baseline: 1.0323x; 1.0323x over previous
//
#include <hip/hip_runtime.h>
#include <math.h>

// FermiNet-like forward, N=1024, DIM=3, all fp32.
//
// v6: pin the register budget from BOTH sides.
//  * v5 evidence: __launch_bounds__(256,4) sets only MIN waves/EU; allocator
//    pursued 8 waves/EU -> 64 VGPR vs ~90 live -> spill came back (2.1 GB
//    FETCH / 470 MB WRITE). Fix: amdgpu_waves_per_eu(4,4) pins min AND max
//    -> allocator targets 128 VGPRs; live ~90 fits; 4 waves/SIMD.
//  * Cooperative h1_fused was 60us WORSE than the plain 4-kernel chain
//    (grid.sync cost) -> reverted to separate l0/lx kernels (v4 tail).
// Unchanged validated pieces: m=2 k2 structure, XOR-swizzled sH (0 bank
// conflicts), barrier-free main loop, reg-hoisted biases, TROW row tables.

#define NP 1024

// ---- workspace offsets (in floats) ----
static const size_t OF_TROW = 0;                    // NP*56 row-major trig
static const size_t OF_CSUM = OF_TROW + NP*56;      // 24  sum_i cos
static const size_t OF_SSUM = OF_CSUM + 24;         // 24  sum_i sin
static const size_t OF_HSUM = OF_SSUM + 24;         // 3*64  h1 row-sum per layer
static const size_t OF_RACC = OF_HSUM + 192;        // 1024  sum_i r(i,j)
static const size_t OF_M0   = OF_RACC + NP;         // 1024*32 sum_i h2 stage0
static const size_t OF_M1   = OF_M0 + NP*32;        // 1024*32 stage1
static const size_t OF_M2   = OF_M1 + NP*32;        // 1024*32 stage2
static const size_t OF_H1A  = OF_M2 + NP*32;        // 1024*64
static const size_t OF_H1B  = OF_H1A + NP*64;       // 1024*64
// end: OF_H1B + NP*64 = 287984 floats (~1.15 MB)

__device__ __forceinline__ float ftanh(float x) {
    float e = __expf(2.0f * x);
    return 1.0f - __fdividef(2.0f, e + 1.0f);
}

// ---------------------------------------------------------------------------
// K1: per-particle trig rows (TROW[i][56]) + column sums + zero HSUM.
// ---------------------------------------------------------------------------
__global__ __launch_bounds__(1024) void k1_tables(
    const float* __restrict__ X,
    float* __restrict__ TROW,
    float* __restrict__ CSUM, float* __restrict__ SSUM,
    float* __restrict__ HSUM)
{
    const int i = threadIdx.x;
    float ck[24], sk[24], cp[3], sp[3];
#pragma unroll
    for (int d = 0; d < 3; ++d) {
        float x = X[i*3 + d];
        sincospif(x, &sp[d], &cp[d]);
#pragma unroll
        for (int k = 0; k < 8; ++k) {
            float s, c;
            sincospif(2.0f*(float)(k+1)*x, &s, &c);
            ck[k*3 + d] = c;  sk[k*3 + d] = s;
        }
    }
    float4* row = (float4*)(TROW + (size_t)i*56);
#pragma unroll
    for (int t = 0; t < 12; ++t)
        row[t] = make_float4(ck[2*t], sk[2*t], ck[2*t+1], sk[2*t+1]);
    row[12] = make_float4(cp[0], sp[0], cp[1], sp[1]);
    row[13] = make_float4(cp[2], sp[2], 0.f, 0.f);

    __shared__ float part[48*16];
    const int lane = i & 63, wv = i >> 6;
#pragma unroll
    for (int v = 0; v < 24; ++v) {
        float a = ck[v], b = sk[v];
#pragma unroll
        for (int off = 32; off; off >>= 1) {
            a += __shfl_down(a, off, 64);
            b += __shfl_down(b, off, 64);
        }
        if (lane == 0) { part[v*16 + wv] = a; part[(24+v)*16 + wv] = b; }
    }
    __syncthreads();
    if (i < 48) {
        float s = 0.f;
#pragma unroll
        for (int w = 0; w < 16; ++w) s += part[i*16 + w];
        if (i < 24) CSUM[i] = s; else SSUM[i-24] = s;
    }
    if (i < 192) HSUM[i] = 0.0f;
}

// ---------------------------------------------------------------------------
// K2: pair kernel. Block = column j. q = tid&7 (cols q*4..q*4+3), g = tid>>3
// (0..31). i = it*64 + m*32 + g, m=0..1, it=0..15. No barriers in main loop.
// waves_per_eu(4,4): allocator targets 128 VGPR (live ~90), HW gets 4
// waves/SIMD. LDS 24.6 KB -> 6 blocks/CU possible, not binding.
// ---------------------------------------------------------------------------
__global__
__attribute__((amdgpu_flat_work_group_size(256, 256), amdgpu_waves_per_eu(4, 4)))
void k2_pairs(
    const float* __restrict__ W20, const float* __restrict__ b20,
    const float* __restrict__ W21, const float* __restrict__ b21,
    const float* __restrict__ W22, const float* __restrict__ b22,
    const float* __restrict__ TROW,
    float* __restrict__ RACC, float* __restrict__ M0,
    float* __restrict__ M1, float* __restrict__ M2)
{
    __shared__ __align__(16) float sW0[49*32];
    __shared__ __align__(16) float sW1[32*32];
    __shared__ __align__(16) float sW2[32*32];
    __shared__ __align__(16) float sH[2*32*32];   // 64 rows x 32 f, XOR-swizzled
    __shared__ __align__(16) float sJ[56];        // row j of TROW
    __shared__ float sPart[4][97];

    const int tid = threadIdx.x;
    const int j = blockIdx.x;
    const int q = tid & 7;
    const int g = tid >> 3;          // 0..31
    const int c0 = q * 4;
    const int gx = g & 7;

    for (int v = tid; v < 49*32; v += 256) sW0[v] = W20[v];
    for (int v = tid; v < 32*32; v += 256) sW1[v] = W21[v];
    for (int v = tid; v < 32*32; v += 256) sW2[v] = W22[v];
    if (tid < 14) ((float4*)sJ)[tid] = ((const float4*)(TROW + (size_t)j*56))[tid];

    // biases: registers, loop-invariant
    float zb0[4], zb1[4], zb2[4];
    *(float4*)zb0 = *(const float4*)(b20 + c0);
    *(float4*)zb1 = *(const float4*)(b21 + c0);
    *(float4*)zb2 = *(const float4*)(b22 + c0);
    __syncthreads();

    float4* sH4 = (float4*)sH;        // index: (m*32+g)*8 + (slot ^ gx)

    float a0[4], a1[4], a2[4];
#pragma unroll
    for (int u = 0; u < 4; ++u) { a0[u] = 0.f; a1[u] = 0.f; a2[u] = 0.f; }
    float racc = 0.f;

#pragma unroll 1
    for (int it = 0; it < 16; ++it) {
        const int ib = it*64 + g;            // rows ib, ib+32
        const float4* row0 = (const float4*)(TROW + (size_t)(ib +  0)*56);
        const float4* row1 = (const float4*)(TROW + (size_t)(ib + 32)*56);

        float z[2][4];
#pragma unroll
        for (int m = 0; m < 2; ++m) {
            z[m][0] = zb0[0]; z[m][1] = zb0[1]; z[m][2] = zb0[2]; z[m][3] = zb0[3];
        }

        // ---- r feature (8x redundant across q-lanes) ----
        float rv[2];
#pragma unroll
        for (int m = 0; m < 2; ++m) {
            const float4* rw = m ? row1 : row0;
            float4 pa = rw[12], pb = rw[13];
            float sd0 = fmaf(pa.y, sJ[48], -(pa.x * sJ[49]));
            float sd1 = fmaf(pa.w, sJ[50], -(pa.z * sJ[51]));
            float sd2 = fmaf(pb.y, sJ[52], -(pb.x * sJ[53]));
            float r2 = fmaf(sd0, sd0, fmaf(sd1, sd1, sd2*sd2));
            rv[m] = sqrtf(r2);
            racc += rv[m];
        }
        {
            const float4 w = *(const float4*)(sW0 + c0);   // row 0
#pragma unroll
            for (int m = 0; m < 2; ++m) {
                z[m][0]=fmaf(rv[m],w.x,z[m][0]); z[m][1]=fmaf(rv[m],w.y,z[m][1]);
                z[m][2]=fmaf(rv[m],w.z,z[m][2]); z[m][3]=fmaf(rv[m],w.w,z[m][3]);
            }
        }
        // ---- 48 cos/sin features, 2 kd per float4 chunk ----
#pragma unroll
        for (int t = 0; t < 12; ++t) {
            const float4 cs0 = row0[t], cs1 = row1[t];
#pragma unroll
            for (int sub = 0; sub < 2; ++sub) {
                const int kd = 2*t + sub;
                const int k = kd/3, d = kd - k*3;
                const float ckj = sJ[2*kd], skj = sJ[2*kd+1];
                const float4 wc  = *(const float4*)(sW0 + (1 + k*6 + d)*32 + c0);
                const float4 wsn = *(const float4*)(sW0 + (4 + k*6 + d)*32 + c0);
#pragma unroll
                for (int m = 0; m < 2; ++m) {
                    const float4 cs = m ? cs1 : cs0;
                    float ci = sub ? cs.z : cs.x;
                    float si = sub ? cs.w : cs.y;
                    float cc = fmaf(ci, ckj, si * skj);
                    float ss = fmaf(si, ckj, -(ci * skj));
                    z[m][0] = fmaf(cc, wc.x, fmaf(ss, wsn.x, z[m][0]));
                    z[m][1] = fmaf(cc, wc.y, fmaf(ss, wsn.y, z[m][1]));
                    z[m][2] = fmaf(cc, wc.z, fmaf(ss, wsn.z, z[m][2]));
                    z[m][3] = fmaf(cc, wc.w, fmaf(ss, wsn.w, z[m][3]));
                }
            }
        }

        // ---- layer 0 tanh; publish h0 to sH ----
        float h0own[2][4];
#pragma unroll
        for (int m = 0; m < 2; ++m) {
            float4 hv;
            hv.x = ftanh(z[m][0]); hv.y = ftanh(z[m][1]);
            hv.z = ftanh(z[m][2]); hv.w = ftanh(z[m][3]);
            h0own[m][0]=hv.x; h0own[m][1]=hv.y; h0own[m][2]=hv.z; h0own[m][3]=hv.w;
            a0[0]+=hv.x; a0[1]+=hv.y; a0[2]+=hv.z; a0[3]+=hv.w;
            sH4[(m*32+g)*8 + (q ^ gx)] = hv;
            z[m][0]=zb1[0]; z[m][1]=zb1[1]; z[m][2]=zb1[2]; z[m][3]=zb1[3];
        }

        // ---- layer 1 matvec (sH written by own wave; no barrier needed) ----
#pragma unroll
        for (int kc = 0; kc < 8; ++kc) {
            const float4 w0 = *(const float4*)(sW1 + (kc*4+0)*32 + c0);
            const float4 w1 = *(const float4*)(sW1 + (kc*4+1)*32 + c0);
            const float4 w2 = *(const float4*)(sW1 + (kc*4+2)*32 + c0);
            const float4 w3 = *(const float4*)(sW1 + (kc*4+3)*32 + c0);
#pragma unroll
            for (int m = 0; m < 2; ++m) {
                const float4 hc = sH4[(m*32+g)*8 + (kc ^ gx)];
                z[m][0]=fmaf(hc.x,w0.x,fmaf(hc.y,w1.x,fmaf(hc.z,w2.x,fmaf(hc.w,w3.x,z[m][0]))));
                z[m][1]=fmaf(hc.x,w0.y,fmaf(hc.y,w1.y,fmaf(hc.z,w2.y,fmaf(hc.w,w3.y,z[m][1]))));
                z[m][2]=fmaf(hc.x,w0.z,fmaf(hc.y,w1.z,fmaf(hc.z,w2.z,fmaf(hc.w,w3.z,z[m][2]))));
                z[m][3]=fmaf(hc.x,w0.w,fmaf(hc.y,w1.w,fmaf(hc.z,w2.w,fmaf(hc.w,w3.w,z[m][3]))));
            }
        }
        float h1own[2][4];
#pragma unroll
        for (int m = 0; m < 2; ++m) {
            float4 hv;
            hv.x = ftanh(z[m][0]) + h0own[m][0];
            hv.y = ftanh(z[m][1]) + h0own[m][1];
            hv.z = ftanh(z[m][2]) + h0own[m][2];
            hv.w = ftanh(z[m][3]) + h0own[m][3];
            h1own[m][0]=hv.x; h1own[m][1]=hv.y; h1own[m][2]=hv.z; h1own[m][3]=hv.w;
            a1[0]+=hv.x; a1[1]+=hv.y; a1[2]+=hv.z; a1[3]+=hv.w;
            sH4[(m*32+g)*8 + (q ^ gx)] = hv;       // overwrite h0 (reads done)
            z[m][0]=zb2[0]; z[m][1]=zb2[1]; z[m][2]=zb2[2]; z[m][3]=zb2[3];
        }

        // ---- layer 2 matvec ----
#pragma unroll
        for (int kc = 0; kc < 8; ++kc) {
            const float4 w0 = *(const float4*)(sW2 + (kc*4+0)*32 + c0);
            const float4 w1 = *(const float4*)(sW2 + (kc*4+1)*32 + c0);
            const float4 w2 = *(const float4*)(sW2 + (kc*4+2)*32 + c0);
            const float4 w3 = *(const float4*)(sW2 + (kc*4+3)*32 + c0);
#pragma unroll
            for (int m = 0; m < 2; ++m) {
                const float4 hc = sH4[(m*32+g)*8 + (kc ^ gx)];
                z[m][0]=fmaf(hc.x,w0.x,fmaf(hc.y,w1.x,fmaf(hc.z,w2.x,fmaf(hc.w,w3.x,z[m][0]))));
                z[m][1]=fmaf(hc.x,w0.y,fmaf(hc.y,w1.y,fmaf(hc.z,w2.y,fmaf(hc.w,w3.y,z[m][1]))));
                z[m][2]=fmaf(hc.x,w0.z,fmaf(hc.y,w1.z,fmaf(hc.z,w2.z,fmaf(hc.w,w3.z,z[m][2]))));
                z[m][3]=fmaf(hc.x,w0.w,fmaf(hc.y,w1.w,fmaf(hc.z,w2.w,fmaf(hc.w,w3.w,z[m][3]))));
            }
        }
#pragma unroll
        for (int m = 0; m < 2; ++m) {
            a2[0] += ftanh(z[m][0]) + h1own[m][0];
            a2[1] += ftanh(z[m][1]) + h1own[m][1];
            a2[2] += ftanh(z[m][2]) + h1own[m][2];
            a2[3] += ftanh(z[m][3]) + h1own[m][3];
        }
    }

    // ---- reduction: over g within wave (lane bits 3..5), then 4 waves ----
    const int lane = tid & 63, wid = tid >> 6;
#pragma unroll
    for (int u = 0; u < 4; ++u) {
#pragma unroll
        for (int mask = 8; mask < 64; mask <<= 1) {
            a0[u] += __shfl_xor(a0[u], mask, 64);
            a1[u] += __shfl_xor(a1[u], mask, 64);
            a2[u] += __shfl_xor(a2[u], mask, 64);
        }
    }
#pragma unroll
    for (int mask = 1; mask < 64; mask <<= 1) racc += __shfl_xor(racc, mask, 64);

    if (lane < 8) {
#pragma unroll
        for (int u = 0; u < 4; ++u) {
            sPart[wid][1  + lane*4 + u] = a0[u];
            sPart[wid][33 + lane*4 + u] = a1[u];
            sPart[wid][65 + lane*4 + u] = a2[u];
        }
    }
    if (lane == 0) sPart[wid][0] = racc;
    __syncthreads();
    if (tid < 97) {
        float s = sPart[0][tid] + sPart[1][tid] + sPart[2][tid] + sPart[3][tid];
        if (tid == 0)      RACC[j] = s * 0.125f;     // r computed 8x redundantly
        else if (tid < 33) M0[j*32 + (tid-1)]  = s;
        else if (tid < 65) M1[j*32 + (tid-33)] = s;
        else               M2[j*32 + (tid-65)] = s;
    }
}

// ---------------------------------------------------------------------------
// Phase B: h1 path. Thread = (row j, 8-channel chunk q). 8192 threads.
// ---------------------------------------------------------------------------
#define FMA8(fv, wptr) do { \
    const float4* w4_ = (const float4*)(wptr); \
    float4 a_ = w4_[0], b_ = w4_[1]; \
    z[0]=fmaf((fv),a_.x,z[0]); z[1]=fmaf((fv),a_.y,z[1]); \
    z[2]=fmaf((fv),a_.z,z[2]); z[3]=fmaf((fv),a_.w,z[3]); \
    z[4]=fmaf((fv),b_.x,z[4]); z[5]=fmaf((fv),b_.y,z[5]); \
    z[6]=fmaf((fv),b_.z,z[6]); z[7]=fmaf((fv),b_.w,z[7]); \
} while (0)

__device__ __forceinline__ void hsum_atomic(float* HS, const float h[8],
                                            int tid, int c0) {
    float hs[8];
#pragma unroll
    for (int u = 0; u < 8; ++u) {
        hs[u] = h[u];
#pragma unroll
        for (int mask = 8; mask < 64; mask <<= 1)
            hs[u] += __shfl_xor(hs[u], mask, 64);
    }
    if (((tid & 63) >> 3) == 0) {
#pragma unroll
        for (int u = 0; u < 8; ++u) atomicAdd(&HS[c0 + u], hs[u]);
    }
}

__global__ __launch_bounds__(256) void l0_kernel(
    const float* __restrict__ Tsc, const float* __restrict__ W10,
    const float* __restrict__ b10,
    const float* __restrict__ TROW,
    const float* __restrict__ CSUM, const float* __restrict__ SSUM,
    const float* __restrict__ RACC,
    float* __restrict__ H1A, float* __restrict__ HSUM0)
{
    const int tid = threadIdx.x;
    const int gid = blockIdx.x*256 + tid;
    const int j = gid >> 3, qq = gid & 7, c0 = qq*8;
    const float inv_n = 1.0f/1024.0f;
    const float t = Tsc[0];

    float z[8];
#pragma unroll
    for (int u = 0; u < 8; ++u) z[u] = b10[c0+u];

    FMA8(t, W10 + 0*64 + c0);
    FMA8(t, W10 + 17*64 + c0);
#pragma unroll
    for (int k = 0; k < 8; ++k) {
        float s, c; sincospif(2.0f*(float)(k+1)*t, &s, &c);
        FMA8(c, W10 + (1+2*k)*64 + c0);
        FMA8(c, W10 + (18+2*k)*64 + c0);
        FMA8(s, W10 + (2+2*k)*64 + c0);
        FMA8(s, W10 + (19+2*k)*64 + c0);
    }
    {
        float rb = RACC[j] * inv_n;
        FMA8(rb, W10 + 34*64 + c0);
    }
    const float4* rj = (const float4*)(TROW + (size_t)j*56);
#pragma unroll
    for (int tt = 0; tt < 12; ++tt) {
        float4 v = rj[tt];
#pragma unroll
        for (int sub = 0; sub < 2; ++sub) {
            const int kd = 2*tt + sub;
            float cj = sub ? v.z : v.x;
            float sj = sub ? v.w : v.y;
            float Cb = CSUM[kd]*inv_n, Sb = SSUM[kd]*inv_n;
            float cm = fmaf(cj, Cb, sj*Sb);
            float sm = fmaf(Sb, cj, -(Cb*sj));
            int k = kd/3, d = kd - k*3;
            FMA8(cm, W10 + (35 + k*6 + d)*64 + c0);
            FMA8(sm, W10 + (38 + k*6 + d)*64 + c0);
        }
    }
    float h[8];
#pragma unroll
    for (int u = 0; u < 8; ++u) {
        h[u] = ftanh(z[u]);                  // layer 0: no residual
        H1A[j*64 + c0 + u] = h[u];
    }
    hsum_atomic(HSUM0, h, tid, c0);
}

template<int LAYER>
__global__ __launch_bounds__(256) void lx_kernel(
    const float* __restrict__ W, const float* __restrict__ b,
    const float* __restrict__ hin, float* __restrict__ hout,
    const float* __restrict__ HSin, float* __restrict__ HSout,
    const float* __restrict__ M,
    const float* __restrict__ Wf, const float* __restrict__ X,
    float* __restrict__ out)
{
    const int tid = threadIdx.x;
    const int gid = blockIdx.x*256 + tid;
    const int j = gid >> 3, qq = gid & 7, c0 = qq*8;
    const float inv_n = 1.0f/1024.0f;

    float z[8];
#pragma unroll
    for (int u = 0; u < 8; ++u) z[u] = b[c0+u];
    const float* hrow = hin + j*64;
#pragma unroll 4
    for (int p = 0; p < 64; ++p) FMA8(hrow[p], W + p*64 + c0);
#pragma unroll 4
    for (int p = 0; p < 64; ++p) FMA8(HSin[p]*inv_n, W + (64+p)*64 + c0);
    const float* mrow = M + j*32;
#pragma unroll 4
    for (int p = 0; p < 32; ++p) FMA8(mrow[p]*inv_n, W + (128+p)*64 + c0);
    float h[8];
#pragma unroll
    for (int u = 0; u < 8; ++u) h[u] = ftanh(z[u]) + hrow[c0+u];  // residual

    if (LAYER < 3) {
#pragma unroll
        for (int u = 0; u < 8; ++u) hout[j*64 + c0 + u] = h[u];
        hsum_atomic(HSout, h, tid, c0);
    } else {
        __shared__ float red[256][3];
        float p0 = 0.f, p1 = 0.f, p2 = 0.f;
#pragma unroll
        for (int u = 0; u < 8; ++u) {
            float hv = h[u];
            const float* wf = Wf + (c0+u)*3;
            p0 = fmaf(hv, wf[0], p0);
            p1 = fmaf(hv, wf[1], p1);
            p2 = fmaf(hv, wf[2], p2);
        }
        red[tid][0] = p0; red[tid][1] = p1; red[tid][2] = p2;
        __syncthreads();
        if (qq == 0) {
            float s0 = 0.f, s1 = 0.f, s2 = 0.f;
#pragma unroll
            for (int r = 0; r < 8; ++r) {
                s0 += red[tid+r][0]; s1 += red[tid+r][1]; s2 += red[tid+r][2];
            }
#pragma unroll
            for (int d = 0; d < 3; ++d) {
                float fx = 2.0f * X[j*3 + d];
                fx = fminf(fmaxf(fx, -10.0f), 10.0f);
                float s = (d == 0 ? s0 : (d == 1 ? s1 : s2));
                out[j*3 + d] = -s * fx;
            }
        }
    }
}

// ---------------------------------------------------------------------------
extern "C" void kernel_launch(void* const* d_in, const int* in_sizes, int n_in,
                              void* d_out, int out_size, void* d_ws, size_t ws_size,
                              hipStream_t stream)
{
    const float* X   = (const float*)d_in[0];
    const float* Tsc = (const float*)d_in[1];
    const float* W10 = (const float*)d_in[2];  const float* b10 = (const float*)d_in[3];
    const float* W11 = (const float*)d_in[4];  const float* b11 = (const float*)d_in[5];
    const float* W12 = (const float*)d_in[6];  const float* b12 = (const float*)d_in[7];
    const float* W13 = (const float*)d_in[8];  const float* b13 = (const float*)d_in[9];
    const float* W20 = (const float*)d_in[10]; const float* b20 = (const float*)d_in[11];
    const float* W21 = (const float*)d_in[12]; const float* b21 = (const float*)d_in[13];
    const float* W22 = (const float*)d_in[14]; const float* b22 = (const float*)d_in[15];
    const float* Wf  = (const float*)d_in[16];

    float* ws  = (float*)d_ws;
    float* out = (float*)d_out;

    float* TROW = ws + OF_TROW;
    float* CSUM = ws + OF_CSUM; float* SSUM = ws + OF_SSUM;
    float* HSUM = ws + OF_HSUM; float* RACC = ws + OF_RACC;
    float* M0 = ws + OF_M0; float* M1 = ws + OF_M1; float* M2 = ws + OF_M2;
    float* H1A = ws + OF_H1A; float* H1B = ws + OF_H1B;

    k1_tables<<<1, 1024, 0, stream>>>(X, TROW, CSUM, SSUM, HSUM);
    k2_pairs<<<NP, 256, 0, stream>>>(W20, b20, W21, b21, W22, b22,
                                     TROW, RACC, M0, M1, M2);
    l0_kernel<<<32, 256, 0, stream>>>(Tsc, W10, b10, TROW, CSUM, SSUM, RACC,
                                      H1A, HSUM + 0*64);
    lx_kernel<1><<<32, 256, 0, stream>>>(W11, b11, H1A, H1B, HSUM + 0*64, HSUM + 1*64,
                                         M0, (const float*)nullptr, (const float*)nullptr,
                                         (float*)nullptr);
    lx_kernel<2><<<32, 256, 0, stream>>>(W12, b12, H1B, H1A, HSUM + 1*64, HSUM + 2*64,
                                         M1, (const float*)nullptr, (const float*)nullptr,
                                         (float*)nullptr);
    lx_kernel<3><<<32, 256, 0, stream>>>(W13, b13, H1A, H1B, HSUM + 2*64, (float*)nullptr,
                                         M2, Wf, X, out);
}

// Round 7
// 535.934 us; speedup vs baseline: 2.0346x; 1.9709x over previous
//
#include <hip/hip_runtime.h>
#include <math.h>

// FermiNet-like forward, N=1024, DIM=3, all fp32.
//
// v7: restructured pair kernel -- lane = pair-row, wave = 4-channel group.
//  * v3-v6 mapped the allocator: it chases the next occupancy tier and
//    spills to get there (min=2 -> 128, min=4/waves_per_eu -> 64 regs w/
//    ~20-reg spill). And even spill-free m=2 is LDS-pipe-bound: 113 wave
//    ds_read_b128 weight reads per K-iter ~ 160+ us floor.
//  * Fix both at once: weights/biases/col-j trig are WAVE-UNIFORM -> scalar
//    s_load path (addresses from kernel args + blockIdx + readfirstlane(wid)
//    only). v_fma with SGPR operand: no VGPR cost, no LDS traffic.
//  * Per-lane live ~50 floats -> 64 VGPR honestly fits -> 8 waves/SIMD.
//  * h0/h1 exchange: XOR-swizzled sH[64][32] double buffer, 2 barriers/tile.
//    Read/write patterns hit the b128 8-access/bank minimum -> 0 conflicts.
//  * Features per-lane from L2-resident TROW (~235 MB aggregate @ L2).
// k1 + h1-path kernels unchanged (validated, absmax 1.9e-6).

#define NP 1024

// ---- workspace offsets (in floats) ----
static const size_t OF_TROW = 0;                    // NP*56 row-major trig
static const size_t OF_CSUM = OF_TROW + NP*56;      // 24  sum_i cos
static const size_t OF_SSUM = OF_CSUM + 24;         // 24  sum_i sin
static const size_t OF_HSUM = OF_SSUM + 24;         // 3*64  h1 row-sum per layer
static const size_t OF_RACC = OF_HSUM + 192;        // 1024  sum_i r(i,j)
static const size_t OF_M0   = OF_RACC + NP;         // 1024*32 sum_i h2 stage0
static const size_t OF_M1   = OF_M0 + NP*32;        // 1024*32 stage1
static const size_t OF_M2   = OF_M1 + NP*32;        // 1024*32 stage2
static const size_t OF_H1A  = OF_M2 + NP*32;        // 1024*64
static const size_t OF_H1B  = OF_H1A + NP*64;       // 1024*64
// end: OF_H1B + NP*64 = 287984 floats (~1.15 MB)

__device__ __forceinline__ float ftanh(float x) {
    float e = __expf(2.0f * x);
    return 1.0f - __fdividef(2.0f, e + 1.0f);
}

// ---------------------------------------------------------------------------
// K1: per-particle trig rows (TROW[i][56]) + column sums + zero HSUM.
// ---------------------------------------------------------------------------
__global__ __launch_bounds__(1024) void k1_tables(
    const float* __restrict__ X,
    float* __restrict__ TROW,
    float* __restrict__ CSUM, float* __restrict__ SSUM,
    float* __restrict__ HSUM)
{
    const int i = threadIdx.x;
    float ck[24], sk[24], cp[3], sp[3];
#pragma unroll
    for (int d = 0; d < 3; ++d) {
        float x = X[i*3 + d];
        sincospif(x, &sp[d], &cp[d]);
#pragma unroll
        for (int k = 0; k < 8; ++k) {
            float s, c;
            sincospif(2.0f*(float)(k+1)*x, &s, &c);
            ck[k*3 + d] = c;  sk[k*3 + d] = s;
        }
    }
    float4* row = (float4*)(TROW + (size_t)i*56);
#pragma unroll
    for (int t = 0; t < 12; ++t)
        row[t] = make_float4(ck[2*t], sk[2*t], ck[2*t+1], sk[2*t+1]);
    row[12] = make_float4(cp[0], sp[0], cp[1], sp[1]);
    row[13] = make_float4(cp[2], sp[2], 0.f, 0.f);

    __shared__ float part[48*16];
    const int lane = i & 63, wv = i >> 6;
#pragma unroll
    for (int v = 0; v < 24; ++v) {
        float a = ck[v], b = sk[v];
#pragma unroll
        for (int off = 32; off; off >>= 1) {
            a += __shfl_down(a, off, 64);
            b += __shfl_down(b, off, 64);
        }
        if (lane == 0) { part[v*16 + wv] = a; part[(24+v)*16 + wv] = b; }
    }
    __syncthreads();
    if (i < 48) {
        float s = 0.f;
#pragma unroll
        for (int w = 0; w < 16; ++w) s += part[i*16 + w];
        if (i < 24) CSUM[i] = s; else SSUM[i-24] = s;
    }
    if (i < 192) HSUM[i] = 0.0f;
}

// ---------------------------------------------------------------------------
// K2: pair kernel. Block = column j, 512 threads = 8 waves.
// lane (0..63) = pair-row within tile; wave wid owns channels 4*wid..4*wid+3.
// 16 tiles of 64 rows. Weights via wave-uniform scalar loads (SGPR).
// ---------------------------------------------------------------------------
__global__ __launch_bounds__(512, 8) void k2_pairs(
    const float* __restrict__ W20, const float* __restrict__ b20,
    const float* __restrict__ W21, const float* __restrict__ b21,
    const float* __restrict__ W22, const float* __restrict__ b22,
    const float* __restrict__ TROW,
    float* __restrict__ RACC, float* __restrict__ M0,
    float* __restrict__ M1, float* __restrict__ M2)
{
    __shared__ __align__(16) float sH0[64*32];   // h0 exchange, XOR-swizzled
    __shared__ __align__(16) float sH1[64*32];   // h1 exchange

    const int tid  = threadIdx.x;
    const int lane = tid & 63;
    const int wid  = __builtin_amdgcn_readfirstlane(tid >> 6);   // 0..7 uniform
    const int c0   = wid * 4;                                    // uniform
    const int j    = blockIdx.x;
    const int lx   = lane & 7;                                   // xor key

    const float* __restrict__ Jrow = TROW + (size_t)j * 56;      // uniform addr

    // biases: wave-uniform -> SGPRs, hoisted out of the loop
    const float b0x = b20[c0+0], b0y = b20[c0+1], b0z = b20[c0+2], b0w = b20[c0+3];
    const float b1x = b21[c0+0], b1y = b21[c0+1], b1z = b21[c0+2], b1w = b21[c0+3];
    const float b2x = b22[c0+0], b2y = b22[c0+1], b2z = b22[c0+2], b2w = b22[c0+3];

    float4* H0w = (float4*)sH0 + lane*8;
    float4* H1w = (float4*)sH1 + lane*8;

    float a0x=0.f,a0y=0.f,a0z=0.f,a0w=0.f;
    float a1x=0.f,a1y=0.f,a1z=0.f,a1w=0.f;
    float a2x=0.f,a2y=0.f,a2z=0.f,a2w=0.f;
    float racc = 0.f;

#pragma unroll 1
    for (int tile = 0; tile < 16; ++tile) {
        const int i = tile*64 + lane;
        const float4* rowp = (const float4*)(TROW + (size_t)i*56);

        // ---- r feature ----
        const float4 pa = rowp[12], pb = rowp[13];
        float sd0 = fmaf(pa.y, Jrow[48], -(pa.x * Jrow[49]));
        float sd1 = fmaf(pa.w, Jrow[50], -(pa.z * Jrow[51]));
        float sd2 = fmaf(pb.y, Jrow[52], -(pb.x * Jrow[53]));
        const float r = sqrtf(fmaf(sd0, sd0, fmaf(sd1, sd1, sd2*sd2)));
        racc += r;

        float z0, z1, z2, z3;
        {   // W0 row 0 (r), uniform scalar reads
            const float* w = W20 + c0;
            z0 = fmaf(r, w[0], b0x); z1 = fmaf(r, w[1], b0y);
            z2 = fmaf(r, w[2], b0z); z3 = fmaf(r, w[3], b0w);
        }
        // ---- 48 cos/sin features, 2 kd per float4 of the lane's row ----
#pragma unroll
        for (int t = 0; t < 12; ++t) {
            const float4 f = rowp[t];
#pragma unroll
            for (int sub = 0; sub < 2; ++sub) {
                const int kd = 2*t + sub;
                const int k = kd/3, d = kd - k*3;
                const float cj = Jrow[2*kd], sj = Jrow[2*kd+1];   // uniform
                const float ci = sub ? f.z : f.x;
                const float si = sub ? f.w : f.y;
                const float cc = fmaf(ci, cj, si*sj);
                const float ss = fmaf(si, cj, -(ci*sj));
                const float* wc = W20 + (1 + k*6 + d)*32 + c0;    // uniform
                const float* ws = W20 + (4 + k*6 + d)*32 + c0;    // uniform
                z0 = fmaf(cc, wc[0], fmaf(ss, ws[0], z0));
                z1 = fmaf(cc, wc[1], fmaf(ss, ws[1], z1));
                z2 = fmaf(cc, wc[2], fmaf(ss, ws[2], z2));
                z3 = fmaf(cc, wc[3], fmaf(ss, ws[3], z3));
            }
        }

        // ---- layer 0 tanh; publish to sH0 ----
        const float h0x = ftanh(z0), h0y = ftanh(z1), h0z = ftanh(z2), h0w = ftanh(z3);
        a0x += h0x; a0y += h0y; a0z += h0z; a0w += h0w;
        H0w[wid ^ lx] = make_float4(h0x, h0y, h0z, h0w);
        __syncthreads();

        // ---- layer 1: z = b1 + h0_full(32) @ W1[:, c0..c0+3] ----
        z0 = b1x; z1 = b1y; z2 = b1z; z3 = b1w;
#pragma unroll
        for (int kc = 0; kc < 8; ++kc) {
            const float4 h = H0w[kc ^ lx];               // channels 4kc..4kc+3
            const float* w0 = W21 + (kc*4+0)*32 + c0;    // uniform
            const float* w1 = W21 + (kc*4+1)*32 + c0;
            const float* w2 = W21 + (kc*4+2)*32 + c0;
            const float* w3 = W21 + (kc*4+3)*32 + c0;
            z0 = fmaf(h.x,w0[0], fmaf(h.y,w1[0], fmaf(h.z,w2[0], fmaf(h.w,w3[0], z0))));
            z1 = fmaf(h.x,w0[1], fmaf(h.y,w1[1], fmaf(h.z,w2[1], fmaf(h.w,w3[1], z1))));
            z2 = fmaf(h.x,w0[2], fmaf(h.y,w1[2], fmaf(h.z,w2[2], fmaf(h.w,w3[2], z2))));
            z3 = fmaf(h.x,w0[3], fmaf(h.y,w1[3], fmaf(h.z,w2[3], fmaf(h.w,w3[3], z3))));
        }
        const float h1x = ftanh(z0) + h0x, h1y = ftanh(z1) + h0y;
        const float h1z = ftanh(z2) + h0z, h1w = ftanh(z3) + h0w;
        a1x += h1x; a1y += h1y; a1z += h1z; a1w += h1w;
        H1w[wid ^ lx] = make_float4(h1x, h1y, h1z, h1w);
        __syncthreads();

        // ---- layer 2 ----
        z0 = b2x; z1 = b2y; z2 = b2z; z3 = b2w;
#pragma unroll
        for (int kc = 0; kc < 8; ++kc) {
            const float4 h = H1w[kc ^ lx];
            const float* w0 = W22 + (kc*4+0)*32 + c0;
            const float* w1 = W22 + (kc*4+1)*32 + c0;
            const float* w2 = W22 + (kc*4+2)*32 + c0;
            const float* w3 = W22 + (kc*4+3)*32 + c0;
            z0 = fmaf(h.x,w0[0], fmaf(h.y,w1[0], fmaf(h.z,w2[0], fmaf(h.w,w3[0], z0))));
            z1 = fmaf(h.x,w0[1], fmaf(h.y,w1[1], fmaf(h.z,w2[1], fmaf(h.w,w3[1], z1))));
            z2 = fmaf(h.x,w0[2], fmaf(h.y,w1[2], fmaf(h.z,w2[2], fmaf(h.w,w3[2], z2))));
            z3 = fmaf(h.x,w0[3], fmaf(h.y,w1[3], fmaf(h.z,w2[3], fmaf(h.w,w3[3], z3))));
        }
        a2x += ftanh(z0) + h1x; a2y += ftanh(z1) + h1y;
        a2z += ftanh(z2) + h1z; a2w += ftanh(z3) + h1w;
    }

    // ---- reductions: full-wave shfl; each wave writes its own 4 channels ----
#pragma unroll
    for (int mask = 1; mask < 64; mask <<= 1) {
        a0x += __shfl_xor(a0x, mask, 64); a0y += __shfl_xor(a0y, mask, 64);
        a0z += __shfl_xor(a0z, mask, 64); a0w += __shfl_xor(a0w, mask, 64);
        a1x += __shfl_xor(a1x, mask, 64); a1y += __shfl_xor(a1y, mask, 64);
        a1z += __shfl_xor(a1z, mask, 64); a1w += __shfl_xor(a1w, mask, 64);
        a2x += __shfl_xor(a2x, mask, 64); a2y += __shfl_xor(a2y, mask, 64);
        a2z += __shfl_xor(a2z, mask, 64); a2w += __shfl_xor(a2w, mask, 64);
        racc += __shfl_xor(racc, mask, 64);
    }
    if (lane == 0) {
        *(float4*)(M0 + j*32 + c0) = make_float4(a0x, a0y, a0z, a0w);
        *(float4*)(M1 + j*32 + c0) = make_float4(a1x, a1y, a1z, a1w);
        *(float4*)(M2 + j*32 + c0) = make_float4(a2x, a2y, a2z, a2w);
        if (wid == 0) RACC[j] = racc;     // every wave computed the same racc
    }
}

// ---------------------------------------------------------------------------
// Phase B: h1 path. Thread = (row j, 8-channel chunk q). 8192 threads.
// ---------------------------------------------------------------------------
#define FMA8(fv, wptr) do { \
    const float4* w4_ = (const float4*)(wptr); \
    float4 a_ = w4_[0], b_ = w4_[1]; \
    z[0]=fmaf((fv),a_.x,z[0]); z[1]=fmaf((fv),a_.y,z[1]); \
    z[2]=fmaf((fv),a_.z,z[2]); z[3]=fmaf((fv),a_.w,z[3]); \
    z[4]=fmaf((fv),b_.x,z[4]); z[5]=fmaf((fv),b_.y,z[5]); \
    z[6]=fmaf((fv),b_.z,z[6]); z[7]=fmaf((fv),b_.w,z[7]); \
} while (0)

__device__ __forceinline__ void hsum_atomic(float* HS, const float h[8],
                                            int tid, int c0) {
    float hs[8];
#pragma unroll
    for (int u = 0; u < 8; ++u) {
        hs[u] = h[u];
#pragma unroll
        for (int mask = 8; mask < 64; mask <<= 1)
            hs[u] += __shfl_xor(hs[u], mask, 64);
    }
    if (((tid & 63) >> 3) == 0) {
#pragma unroll
        for (int u = 0; u < 8; ++u) atomicAdd(&HS[c0 + u], hs[u]);
    }
}

__global__ __launch_bounds__(256) void l0_kernel(
    const float* __restrict__ Tsc, const float* __restrict__ W10,
    const float* __restrict__ b10,
    const float* __restrict__ TROW,
    const float* __restrict__ CSUM, const float* __restrict__ SSUM,
    const float* __restrict__ RACC,
    float* __restrict__ H1A, float* __restrict__ HSUM0)
{
    const int tid = threadIdx.x;
    const int gid = blockIdx.x*256 + tid;
    const int j = gid >> 3, qq = gid & 7, c0 = qq*8;
    const float inv_n = 1.0f/1024.0f;
    const float t = Tsc[0];

    float z[8];
#pragma unroll
    for (int u = 0; u < 8; ++u) z[u] = b10[c0+u];

    FMA8(t, W10 + 0*64 + c0);
    FMA8(t, W10 + 17*64 + c0);
#pragma unroll
    for (int k = 0; k < 8; ++k) {
        float s, c; sincospif(2.0f*(float)(k+1)*t, &s, &c);
        FMA8(c, W10 + (1+2*k)*64 + c0);
        FMA8(c, W10 + (18+2*k)*64 + c0);
        FMA8(s, W10 + (2+2*k)*64 + c0);
        FMA8(s, W10 + (19+2*k)*64 + c0);
    }
    {
        float rb = RACC[j] * inv_n;
        FMA8(rb, W10 + 34*64 + c0);
    }
    const float4* rj = (const float4*)(TROW + (size_t)j*56);
#pragma unroll
    for (int tt = 0; tt < 12; ++tt) {
        float4 v = rj[tt];
#pragma unroll
        for (int sub = 0; sub < 2; ++sub) {
            const int kd = 2*tt + sub;
            float cj = sub ? v.z : v.x;
            float sj = sub ? v.w : v.y;
            float Cb = CSUM[kd]*inv_n, Sb = SSUM[kd]*inv_n;
            float cm = fmaf(cj, Cb, sj*Sb);
            float sm = fmaf(Sb, cj, -(Cb*sj));
            int k = kd/3, d = kd - k*3;
            FMA8(cm, W10 + (35 + k*6 + d)*64 + c0);
            FMA8(sm, W10 + (38 + k*6 + d)*64 + c0);
        }
    }
    float h[8];
#pragma unroll
    for (int u = 0; u < 8; ++u) {
        h[u] = ftanh(z[u]);                  // layer 0: no residual
        H1A[j*64 + c0 + u] = h[u];
    }
    hsum_atomic(HSUM0, h, tid, c0);
}

template<int LAYER>
__global__ __launch_bounds__(256) void lx_kernel(
    const float* __restrict__ W, const float* __restrict__ b,
    const float* __restrict__ hin, float* __restrict__ hout,
    const float* __restrict__ HSin, float* __restrict__ HSout,
    const float* __restrict__ M,
    const float* __restrict__ Wf, const float* __restrict__ X,
    float* __restrict__ out)
{
    const int tid = threadIdx.x;
    const int gid = blockIdx.x*256 + tid;
    const int j = gid >> 3, qq = gid & 7, c0 = qq*8;
    const float inv_n = 1.0f/1024.0f;

    float z[8];
#pragma unroll
    for (int u = 0; u < 8; ++u) z[u] = b[c0+u];
    const float* hrow = hin + j*64;
#pragma unroll 4
    for (int p = 0; p < 64; ++p) FMA8(hrow[p], W + p*64 + c0);
#pragma unroll 4
    for (int p = 0; p < 64; ++p) FMA8(HSin[p]*inv_n, W + (64+p)*64 + c0);
    const float* mrow = M + j*32;
#pragma unroll 4
    for (int p = 0; p < 32; ++p) FMA8(mrow[p]*inv_n, W + (128+p)*64 + c0);
    float h[8];
#pragma unroll
    for (int u = 0; u < 8; ++u) h[u] = ftanh(z[u]) + hrow[c0+u];  // residual

    if (LAYER < 3) {
#pragma unroll
        for (int u = 0; u < 8; ++u) hout[j*64 + c0 + u] = h[u];
        hsum_atomic(HSout, h, tid, c0);
    } else {
        __shared__ float red[256][3];
        float p0 = 0.f, p1 = 0.f, p2 = 0.f;
#pragma unroll
        for (int u = 0; u < 8; ++u) {
            float hv = h[u];
            const float* wf = Wf + (c0+u)*3;
            p0 = fmaf(hv, wf[0], p0);
            p1 = fmaf(hv, wf[1], p1);
            p2 = fmaf(hv, wf[2], p2);
        }
        red[tid][0] = p0; red[tid][1] = p1; red[tid][2] = p2;
        __syncthreads();
        if (qq == 0) {
            float s0 = 0.f, s1 = 0.f, s2 = 0.f;
#pragma unroll
            for (int r = 0; r < 8; ++r) {
                s0 += red[tid+r][0]; s1 += red[tid+r][1]; s2 += red[tid+r][2];
            }
#pragma unroll
            for (int d = 0; d < 3; ++d) {
                float fx = 2.0f * X[j*3 + d];
                fx = fminf(fmaxf(fx, -10.0f), 10.0f);
                float s = (d == 0 ? s0 : (d == 1 ? s1 : s2));
                out[j*3 + d] = -s * fx;
            }
        }
    }
}

// ---------------------------------------------------------------------------
extern "C" void kernel_launch(void* const* d_in, const int* in_sizes, int n_in,
                              void* d_out, int out_size, void* d_ws, size_t ws_size,
                              hipStream_t stream)
{
    const float* X   = (const float*)d_in[0];
    const float* Tsc = (const float*)d_in[1];
    const float* W10 = (const float*)d_in[2];  const float* b10 = (const float*)d_in[3];
    const float* W11 = (const float*)d_in[4];  const float* b11 = (const float*)d_in[5];
    const float* W12 = (const float*)d_in[6];  const float* b12 = (const float*)d_in[7];
    const float* W13 = (const float*)d_in[8];  const float* b13 = (const float*)d_in[9];
    const float* W20 = (const float*)d_in[10]; const float* b20 = (const float*)d_in[11];
    const float* W21 = (const float*)d_in[12]; const float* b21 = (const float*)d_in[13];
    const float* W22 = (const float*)d_in[14]; const float* b22 = (const float*)d_in[15];
    const float* Wf  = (const float*)d_in[16];

    float* ws  = (float*)d_ws;
    float* out = (float*)d_out;

    float* TROW = ws + OF_TROW;
    float* CSUM = ws + OF_CSUM; float* SSUM = ws + OF_SSUM;
    float* HSUM = ws + OF_HSUM; float* RACC = ws + OF_RACC;
    float* M0 = ws + OF_M0; float* M1 = ws + OF_M1; float* M2 = ws + OF_M2;
    float* H1A = ws + OF_H1A; float* H1B = ws + OF_H1B;

    k1_tables<<<1, 1024, 0, stream>>>(X, TROW, CSUM, SSUM, HSUM);
    k2_pairs<<<NP, 512, 0, stream>>>(W20, b20, W21, b21, W22, b22,
                                     TROW, RACC, M0, M1, M2);
    l0_kernel<<<32, 256, 0, stream>>>(Tsc, W10, b10, TROW, CSUM, SSUM, RACC,
                                      H1A, HSUM + 0*64);
    lx_kernel<1><<<32, 256, 0, stream>>>(W11, b11, H1A, H1B, HSUM + 0*64, HSUM + 1*64,
                                         M0, (const float*)nullptr, (const float*)nullptr,
                                         (float*)nullptr);
    lx_kernel<2><<<32, 256, 0, stream>>>(W12, b12, H1B, H1A, HSUM + 1*64, HSUM + 2*64,
                                         M1, (const float*)nullptr, (const float*)nullptr,
                                         (float*)nullptr);
    lx_kernel<3><<<32, 256, 0, stream>>>(W13, b13, H1A, H1B, HSUM + 2*64, (float*)nullptr,
                                         M2, Wf, X, out);
}